// Round 1
// baseline (1049.763 us; speedup 1.0000x reference)
//
#include <hip/hip_runtime.h>
#include <hip/hip_bf16.h>

#define DI __device__ __forceinline__

typedef __attribute__((ext_vector_type(8))) short          s8v;   // 8 x bf16 bit-patterns
typedef __attribute__((ext_vector_type(4))) float          f4v;
typedef __attribute__((ext_vector_type(4))) unsigned short us4v;

DI unsigned short f2bf(float f) {
  unsigned u = __builtin_bit_cast(unsigned, f);
  u += 0x7fffu + ((u >> 16) & 1u);          // round-to-nearest-even
  return (unsigned short)(u >> 16);
}

// ---------------------------------------------------------------------------
// Generic tall-skinny GEMM:  C[M x BN] = op( A[M x K](f32) @ B^T[BN x K](bf16) )
//   A is converted f32->bf16 during staging (reg -> cvt -> XOR-swizzled LDS).
//   B is staged with global_load_lds (16B), source pre-swizzled so that the
//   swizzled ds_read_b128 fragment reads are bank-even.
//   OUT_TBF16: write C transposed as bf16 [BN][M] (B-form for the next GEMM).
// ---------------------------------------------------------------------------
template<int BN, bool HAS_BIAS, bool DO_RELU, bool OUT_TBF16>
__global__ __launch_bounds__(256)
void gemm_k(const float* __restrict__ A, long lda,
            const unsigned short* __restrict__ Bt, long ldb,   // [BN][K] bf16
            const float* __restrict__ bias,
            void* __restrict__ C, long ldc,
            int M, int K)
{
  constexpr int BM  = 32;
  constexpr int WN  = BN / 4;              // per-wave column span
  constexpr int FN  = WN / 16;             // 2 (BN=128) or 1 (BN=64)
  constexpr int FM  = 2;                   // 32 rows = 2 x 16
  constexpr int BIT = (BN * 128) / (256 * 16);   // global_load_lds iters for B

  __shared__ unsigned short As[2][BM * 64];      // [row][64 bf16] swizzled
  __shared__ unsigned short Bs[2][BN * 64];      // [n][64 bf16]  swizzled

  const int tid  = threadIdx.x;
  const int lane = tid & 63;
  const int w    = tid >> 6;
  const int lr   = lane & 15;
  const int lq   = lane >> 4;
  const int m0   = blockIdx.x * BM;
  const int nsteps = (K + 63) >> 6;

  f4v acc[FM][FN] = {};

  // ---- A staging geometry: 256 slots of 16B (8 bf16 = 8 k-elems = 32B f32)
  const int arow = tid >> 3;               // 0..31
  const int as3  = tid & 7;                // 16B slot within 128B row
  int am = m0 + arow; if (am > M - 1) am = M - 1;      // clamp M edge
  const float* aptr = A + (long)am * lda + as3 * 8;
  const int abyte = arow * 128 + ((as3 * 16) ^ ((arow & 7) << 4));

  float areg[8];

  auto a_issue = [&](int k0) {
    if (k0 + 63 < K) {                     // full K-step (uniform branch)
      f4v v0 = *(const f4v*)(aptr + k0);
      f4v v1 = *(const f4v*)(aptr + k0 + 4);
      areg[0]=v0[0]; areg[1]=v0[1]; areg[2]=v0[2]; areg[3]=v0[3];
      areg[4]=v1[0]; areg[5]=v1[1]; areg[6]=v1[2]; areg[7]=v1[3];
    } else {                               // K tail: zero-fill (kills B garbage)
      #pragma unroll
      for (int i = 0; i < 8; i++) {
        int kg = k0 + as3 * 8 + i;
        areg[i] = (kg < K) ? aptr[k0 + i] : 0.f;
      }
    }
  };

  auto a_write = [&](int buf) {
    s8v av;
    #pragma unroll
    for (int i = 0; i < 8; i++) av[i] = (short)f2bf(areg[i]);
    *(s8v*)((char*)&As[buf][0] + abyte) = av;
  };

  auto b_issue = [&](int k0, int buf) {
    #pragma unroll
    for (int i = 0; i < BIT; i++) {
      int o   = (i * 256 + tid) * 16;      // linear LDS byte offset this lane fills
      int row = o >> 7;                    // n index
      int kb  = (o & 127) ^ ((row & 7) << 4);    // pre-swizzled k-byte in tile
      const char* src = (const char*)Bt + (long)row * (ldb * 2) + (long)k0 * 2 + kb;
      char* dst = (char*)&Bs[buf][0] + (i * 256 + (tid & ~63)) * 16;  // wave-uniform base
      __builtin_amdgcn_global_load_lds(
          (const __attribute__((address_space(1))) unsigned int*)src,
          (__attribute__((address_space(3))) unsigned int*)dst, 16, 0, 0);
    }
  };

  auto compute = [&](int buf) {
    #pragma unroll
    for (int kk = 0; kk < 2; kk++) {
      s8v a[FM], b[FN];
      #pragma unroll
      for (int mi = 0; mi < FM; mi++) {
        int row = mi * 16 + lr;
        int off = row * 128 + ((kk * 64 + lq * 16) ^ ((row & 7) << 4));
        a[mi] = *(const s8v*)((const char*)&As[buf][0] + off);
      }
      #pragma unroll
      for (int ni = 0; ni < FN; ni++) {
        int n   = w * WN + ni * 16 + lr;
        int off = n * 128 + ((kk * 64 + lq * 16) ^ ((n & 7) << 4));
        b[ni] = *(const s8v*)((const char*)&Bs[buf][0] + off);
      }
      #pragma unroll
      for (int mi = 0; mi < FM; mi++)
        #pragma unroll
        for (int ni = 0; ni < FN; ni++)
          acc[mi][ni] = __builtin_amdgcn_mfma_f32_16x16x32_bf16(
              a[mi], b[ni], acc[mi][ni], 0, 0, 0);
    }
  };

  // ---- prologue: stage tile 0
  a_issue(0);
  b_issue(0, 0);
  a_write(0);
  __syncthreads();

  // ---- 2-phase double-buffered main loop (issue next loads BEFORE compute)
  int buf = 0;
  for (int t = 0; t < nsteps; t++) {
    const bool more = (t + 1 < nsteps);
    if (more) { a_issue((t + 1) << 6); b_issue((t + 1) << 6, buf ^ 1); }
    compute(buf);
    if (more) a_write(buf ^ 1);
    __syncthreads();
    buf ^= 1;
  }

  // ---- epilogue  (C/D frag: col = lane&15, row = (lane>>4)*4 + r)
  #pragma unroll
  for (int mi = 0; mi < FM; mi++) {
    #pragma unroll
    for (int ni = 0; ni < FN; ni++) {
      const int n  = w * WN + ni * 16 + lr;
      const int mb = m0 + mi * 16 + lq * 4;
      f4v v = acc[mi][ni];
      if (HAS_BIAS) {
        const float bv = bias[n];
        v[0] += bv; v[1] += bv; v[2] += bv; v[3] += bv;
      }
      if (DO_RELU) {
        v[0] = fmaxf(v[0], 0.f); v[1] = fmaxf(v[1], 0.f);
        v[2] = fmaxf(v[2], 0.f); v[3] = fmaxf(v[3], 0.f);
      }
      if (OUT_TBF16) {
        if (mb < M) {                       // group-aligned (M % 4 == 0)
          us4v o;
          o[0] = f2bf(v[0]); o[1] = f2bf(v[1]); o[2] = f2bf(v[2]); o[3] = f2bf(v[3]);
          *(us4v*)((unsigned short*)C + (long)n * ldc + mb) = o;
        }
      } else {
        float* Cf = (float*)C;
        #pragma unroll
        for (int r = 0; r < 4; r++)
          if (mb + r < M) Cf[(long)(mb + r) * ldc + n] = v[r];
      }
    }
  }
}

// ---------------------------------------------------------------------------
// Convert the 5 weight matrices f32 -> bf16 (row-major [out][k] == B-form).
// Segment offsets: W0 65536 | W1 16384 | W2 8192 | Wp1 4096 | Wp2 4096
// ---------------------------------------------------------------------------
__global__ __launch_bounds__(256)
void wconv(const float* __restrict__ w0, const float* __restrict__ w1,
           const float* __restrict__ w2, const float* __restrict__ wp1,
           const float* __restrict__ wp2, unsigned short* __restrict__ out)
{
  int i = blockIdx.x * 256 + threadIdx.x;
  const float* src; int off;
  if      (i < 65536) { src = w0;  off = i; }
  else if (i < 81920) { src = w1;  off = i - 65536; }
  else if (i < 90112) { src = w2;  off = i - 81920; }
  else if (i < 94208) { src = wp1; off = i - 90112; }
  else if (i < 98304) { src = wp2; off = i - 94208; }
  else return;
  out[i] = f2bf(src[off]);
}

// ---------------------------------------------------------------------------
extern "C" void kernel_launch(void* const* d_in, const int* in_sizes, int n_in,
                              void* d_out, int out_size, void* d_ws, size_t ws_size,
                              hipStream_t stream)
{
  const float* x   = (const float*)d_in[0];   // [10000][512]
  const float* Adj = (const float*)d_in[1];   // [10000][10000]
  const float* W0  = (const float*)d_in[2];
  const float* b0  = (const float*)d_in[3];
  const float* W1  = (const float*)d_in[4];
  const float* b1  = (const float*)d_in[5];
  const float* W2  = (const float*)d_in[6];
  const float* b2  = (const float*)d_in[7];
  const float* Wp1 = (const float*)d_in[8];
  const float* bp1 = (const float*)d_in[9];
  const float* Wp2 = (const float*)d_in[10];
  const float* bp2 = (const float*)d_in[11];

  float* z_out   = (float*)d_out;             // [10000][64]
  float* emb_out = (float*)d_out + 640000;    // [10000][64]

  char* ws = (char*)d_ws;                     // ~19.4 MB used
  unsigned short* Wb  = (unsigned short*)(ws + 0);          // 98304 bf16
  unsigned short* P0T = (unsigned short*)(ws + 196608);     // [128][10000] bf16 (+pad)
  float*          H0  = (float*)(ws + 2756864);             // [10000][128] f32
  unsigned short* P1T = (unsigned short*)(ws + 7876864);    // [128][10000] bf16 (+pad)
  float*          H1  = (float*)(ws + 10437120);            // [10000][128] f32
  unsigned short* P2T = (unsigned short*)(ws + 15557120);   // [64][10000] bf16 (+pad)
  float*          Tb  = (float*)(ws + 16837376);            // [10000][64] f32

  dim3 blk(256);
  const int TILES = 313;                      // ceil(10000/32)

  wconv<<<dim3(384), blk, 0, stream>>>(W0, W1, W2, Wp1, Wp2, Wb);

  // P0^T = (x @ W0^T + b0)^T                               [128][10000] bf16
  gemm_k<128,true ,false,true ><<<TILES, blk, 0, stream>>>(x,   512,   Wb,       512,   b0,      P0T,     10000, 10000, 512);
  // H0 = relu(Adj @ P0)                                    [10000][128] f32
  gemm_k<128,false,true ,false><<<TILES, blk, 0, stream>>>(Adj, 10000, P0T,      10000, nullptr, H0,      128,   10000, 10000);
  // P1^T = (H0 @ W1^T + b1)^T
  gemm_k<128,true ,false,true ><<<TILES, blk, 0, stream>>>(H0,  128,   Wb+65536, 128,   b1,      P1T,     10000, 10000, 128);
  // H1 = relu(Adj @ P1)
  gemm_k<128,false,true ,false><<<TILES, blk, 0, stream>>>(Adj, 10000, P1T,      10000, nullptr, H1,      128,   10000, 10000);
  // P2^T = (H1 @ W2^T + b2)^T                              [64][10000] bf16
  gemm_k<64 ,true ,false,true ><<<TILES, blk, 0, stream>>>(H1,  128,   Wb+81920, 128,   b2,      P2T,     10000, 10000, 128);
  // emb = Adj @ P2  (no relu)  -> d_out second half
  gemm_k<64 ,false,false,false><<<TILES, blk, 0, stream>>>(Adj, 10000, P2T,      10000, nullptr, emb_out, 64,    10000, 10000);
  // T = relu(emb @ Wp1^T + bp1)
  gemm_k<64 ,true ,true ,false><<<TILES, blk, 0, stream>>>(emb_out, 64, Wb+90112, 64,   bp1,     Tb,      64,    10000, 64);
  // z = T @ Wp2^T + bp2  -> d_out first half
  gemm_k<64 ,true ,false,false><<<TILES, blk, 0, stream>>>(Tb,  64,   Wb+94208,  64,    bp2,     z_out,   64,    10000, 64);
}

// Round 3
// 801.488 us; speedup vs baseline: 1.3098x; 1.3098x over previous
//
#include <hip/hip_runtime.h>
#include <hip/hip_bf16.h>

#define DI __device__ __forceinline__

typedef __attribute__((ext_vector_type(8))) short          s8v;   // 8 x bf16 bit-patterns
typedef __attribute__((ext_vector_type(4))) float          f4v;
typedef __attribute__((ext_vector_type(4))) unsigned short us4v;

DI unsigned short f2bf(float f) {
  unsigned u = __builtin_bit_cast(unsigned, f);
  u += 0x7fffu + ((u >> 16) & 1u);          // round-to-nearest-even
  return (unsigned short)(u >> 16);
}

static constexpr long LDP = 10048;          // padded K-stride for bf16 panels

// Stage ROWS x 64 bf16 tile into XOR-swizzled LDS via global_load_lds(16B).
// Source address pre-swizzled; LDS dest linear (both-sides-or-neither rule).
template<int ROWS>
DI void stage_lds(const unsigned short* __restrict__ src, long ld, int r0, int k0,
                  unsigned short* lds, int tid) {
  constexpr int IT = (ROWS * 128) / 4096;   // 16B slots / 256 threads
  #pragma unroll
  for (int i = 0; i < IT; i++) {
    const int o   = (i * 256 + tid) * 16;   // linear LDS byte this lane fills
    const int row = o >> 7;
    const int kb  = (o & 127) ^ ((row & 7) << 4);
    const char* s = (const char*)(src + (long)(r0 + row) * ld + k0) + kb;
    char* d = (char*)lds + (i * 256 + (tid & ~63)) * 16;   // wave-uniform base
    __builtin_amdgcn_global_load_lds(
        (const __attribute__((address_space(1))) unsigned int*)s,
        (__attribute__((address_space(3))) unsigned int*)d, 16, 0, 0);
  }
}

// ---------------------------------------------------------------------------
// C[M x BN] = op( A[M x K] @ B^T[BN x K](bf16) )   BM=32, BK=64, 4 waves
//  ABF16:  A is bf16 row-major (padded ld) -> pure global_load_lds staging
//  !ABF16: A is f32 -> reg-stage + cvt + swizzled ds_write (M-edge clamped)
//  MIRROR: write the cvt'd A tile to a global bf16 mirror (Adj f32 -> bf16)
//  SPLITK: grid.y = split; raw f32 partials at C + s*M*ldc (no bias/relu)
// ---------------------------------------------------------------------------
template<int BN, int SPLITK, bool ABF16, bool MIRROR, bool HAS_BIAS, bool DO_RELU, bool OUT_TBF16>
__global__ __launch_bounds__(256)
void gemm_k(const void* __restrict__ Avoid, long lda,
            const unsigned short* __restrict__ Bt, long ldb,
            const float* __restrict__ bias,
            void* __restrict__ C, long ldc,
            int M, int K,
            unsigned short* __restrict__ mirror, long mld)
{
  constexpr int BM = 32;
  constexpr int WN = BN / 4;
  constexpr int FN = WN / 16;               // 2 (BN=128) or 1 (BN=64)
  constexpr int FM = 2;

  __shared__ unsigned short As[2][BM * 64];
  __shared__ unsigned short Bs[2][BN * 64];

  const int tid  = threadIdx.x;
  const int lane = tid & 63;
  const int w    = tid >> 6;
  const int lr   = lane & 15;
  const int lq   = lane >> 4;
  const int m0   = blockIdx.x * BM;
  const int s    = (SPLITK > 1) ? blockIdx.y : 0;

  // K-range for this split (64-aligned except the global tail)
  const int tsteps = (K + 63) >> 6;
  const int base_  = tsteps / SPLITK, rem_ = tsteps % SPLITK;
  const int sbeg   = s * base_ + (s < rem_ ? s : rem_);
  const int send   = sbeg + base_ + (s < rem_ ? 1 : 0);
  const int kbeg   = sbeg << 6;
  const int kend   = (send << 6) < K ? (send << 6) : K;
  const int nsteps = send - sbeg;

  f4v acc[FM][FN] = {};

  // ---- f32 A staging state
  const int arow = tid >> 3;
  const int as3  = tid & 7;
  int am = m0 + arow; if (am > M - 1) am = M - 1;
  const float* aptr = (const float*)Avoid + (long)am * lda + as3 * 8;
  const int abyte = arow * 128 + ((as3 * 16) ^ ((arow & 7) << 4));
  float areg[8];
  int   akur = 0;

  auto a_issue = [&](int k0) {
    akur = k0;
    if (k0 + 63 < kend) {
      f4v v0 = *(const f4v*)(aptr + k0);
      f4v v1 = *(const f4v*)(aptr + k0 + 4);
      areg[0]=v0[0]; areg[1]=v0[1]; areg[2]=v0[2]; areg[3]=v0[3];
      areg[4]=v1[0]; areg[5]=v1[1]; areg[6]=v1[2]; areg[7]=v1[3];
    } else {
      #pragma unroll
      for (int i = 0; i < 8; i++) {
        int kg = k0 + as3 * 8 + i;
        areg[i] = (kg < kend) ? aptr[k0 + i] : 0.f;
      }
    }
  };

  auto a_write = [&](int buf) {
    s8v av;
    #pragma unroll
    for (int i = 0; i < 8; i++) av[i] = (short)f2bf(areg[i]);
    *(s8v*)((char*)&As[buf][0] + abyte) = av;
    if (MIRROR)
      *(s8v*)(mirror + (long)am * mld + akur + as3 * 8) = av;
  };

  auto compute = [&](int buf) {
    #pragma unroll
    for (int kk = 0; kk < 2; kk++) {
      s8v a[FM], b[FN];
      #pragma unroll
      for (int mi = 0; mi < FM; mi++) {
        int row = mi * 16 + lr;
        int off = row * 128 + ((kk * 64 + lq * 16) ^ ((row & 7) << 4));
        a[mi] = *(const s8v*)((const char*)&As[buf][0] + off);
      }
      #pragma unroll
      for (int ni = 0; ni < FN; ni++) {
        int n   = w * WN + ni * 16 + lr;
        int off = n * 128 + ((kk * 64 + lq * 16) ^ ((n & 7) << 4));
        b[ni] = *(const s8v*)((const char*)&Bs[buf][0] + off);
      }
      #pragma unroll
      for (int mi = 0; mi < FM; mi++)
        #pragma unroll
        for (int ni = 0; ni < FN; ni++)
          acc[mi][ni] = __builtin_amdgcn_mfma_f32_16x16x32_bf16(
              a[mi], b[ni], acc[mi][ni], 0, 0, 0);
    }
  };

  // ---- prologue: stage tile 0
  if (!ABF16) a_issue(kbeg);
  else        stage_lds<BM>((const unsigned short*)Avoid, lda, m0, kbeg, &As[0][0], tid);
  stage_lds<BN>(Bt, ldb, 0, kbeg, &Bs[0][0], tid);
  if (!ABF16) a_write(0);
  __syncthreads();

  // ---- 2-phase double-buffered loop (issue next loads BEFORE compute)
  int buf = 0;
  for (int t = 0; t < nsteps; t++) {
    const bool more = (t + 1 < nsteps);
    const int  kn   = kbeg + ((t + 1) << 6);
    if (more) {
      if (!ABF16) a_issue(kn);
      else        stage_lds<BM>((const unsigned short*)Avoid, lda, m0, kn, &As[buf ^ 1][0], tid);
      stage_lds<BN>(Bt, ldb, 0, kn, &Bs[buf ^ 1][0], tid);
    }
    compute(buf);
    if (!ABF16 && more) a_write(buf ^ 1);
    __syncthreads();
    buf ^= 1;
  }

  // ---- epilogue  (C/D frag: col = lane&15, row = (lane>>4)*4 + r)
  #pragma unroll
  for (int mi = 0; mi < FM; mi++) {
    #pragma unroll
    for (int ni = 0; ni < FN; ni++) {
      const int n  = w * WN + ni * 16 + lr;
      const int mb = m0 + mi * 16 + lq * 4;
      f4v v = acc[mi][ni];
      if (HAS_BIAS) {
        const float bv = bias[n];
        v[0] += bv; v[1] += bv; v[2] += bv; v[3] += bv;
      }
      if (DO_RELU) {
        v[0] = fmaxf(v[0], 0.f); v[1] = fmaxf(v[1], 0.f);
        v[2] = fmaxf(v[2], 0.f); v[3] = fmaxf(v[3], 0.f);
      }
      if (SPLITK > 1) {
        float* Cf = (float*)C + (long)s * M * ldc;
        #pragma unroll
        for (int r = 0; r < 4; r++)
          if (mb + r < M) Cf[(long)(mb + r) * ldc + n] = v[r];
      } else if (OUT_TBF16) {
        if (mb < M) {
          us4v o;
          o[0] = f2bf(v[0]); o[1] = f2bf(v[1]); o[2] = f2bf(v[2]); o[3] = f2bf(v[3]);
          *(us4v*)((unsigned short*)C + (long)n * ldc + mb) = o;
        }
      } else {
        float* Cf = (float*)C;
        #pragma unroll
        for (int r = 0; r < 4; r++)
          if (mb + r < M) Cf[(long)(mb + r) * ldc + n] = v[r];
      }
    }
  }
}

// out = op(p[0] + p[1] + p[2] + p[3]) over split-K partials, vectorized f4v
template<bool RELU>
__global__ __launch_bounds__(256)
void reduce4(const float* __restrict__ p, float* __restrict__ out, int n4, long s4) {
  int i = blockIdx.x * 256 + threadIdx.x;
  if (i >= n4) return;
  const f4v* pv = (const f4v*)p;
  f4v v = pv[i] + pv[i + s4] + pv[i + 2 * s4] + pv[i + 3 * s4];
  if (RELU) {
    v[0] = fmaxf(v[0], 0.f); v[1] = fmaxf(v[1], 0.f);
    v[2] = fmaxf(v[2], 0.f); v[3] = fmaxf(v[3], 0.f);
  }
  ((f4v*)out)[i] = v;
}

// zero the K-pad [10000,10048) of every bf16 panel row (ws is re-poisoned 0xAA)
__global__ __launch_bounds__(256)
void padzero(unsigned short* p0, unsigned short* p1, unsigned short* p2,
             unsigned short* adjb) {
  int i = blockIdx.x * 256 + threadIdx.x;
  if (i >= 10320 * 12) return;
  int r = i / 12, c = i % 12;
  unsigned short* b;
  if      (r < 128)  b = p0   + (long)r * LDP;
  else if (r < 256)  b = p1   + (long)(r - 128) * LDP;
  else if (r < 320)  b = p2   + (long)(r - 256) * LDP;
  else               b = adjb + (long)(r - 320) * LDP;
  us4v z = {0, 0, 0, 0};
  *(us4v*)(b + 10000 + c * 4) = z;
}

// weights f32 -> bf16, row-major [out][k] (already B-form)
__global__ __launch_bounds__(256)
void wconv(const float* __restrict__ w0, const float* __restrict__ w1,
           const float* __restrict__ w2, const float* __restrict__ wp1,
           const float* __restrict__ wp2, unsigned short* __restrict__ out)
{
  int i = blockIdx.x * 256 + threadIdx.x;
  const float* src; int off;
  if      (i < 65536) { src = w0;  off = i; }
  else if (i < 81920) { src = w1;  off = i - 65536; }
  else if (i < 90112) { src = w2;  off = i - 81920; }
  else if (i < 94208) { src = wp1; off = i - 90112; }
  else if (i < 98304) { src = wp2; off = i - 94208; }
  else return;
  out[i] = f2bf(src[off]);
}

// ---------------------------------------------------------------------------
extern "C" void kernel_launch(void* const* d_in, const int* in_sizes, int n_in,
                              void* d_out, int out_size, void* d_ws, size_t ws_size,
                              hipStream_t stream)
{
  const float* x   = (const float*)d_in[0];
  const float* Adj = (const float*)d_in[1];
  const float* W0  = (const float*)d_in[2];
  const float* b0  = (const float*)d_in[3];
  const float* W1  = (const float*)d_in[4];
  const float* b1  = (const float*)d_in[5];
  const float* W2  = (const float*)d_in[6];
  const float* b2  = (const float*)d_in[7];
  const float* Wp1 = (const float*)d_in[8];
  const float* bp1 = (const float*)d_in[9];
  const float* Wp2 = (const float*)d_in[10];
  const float* bp2 = (const float*)d_in[11];

  float* z_out   = (float*)d_out;             // [10000][64]
  float* emb_out = (float*)d_out + 640000;    // [10000][64]

  char* ws = (char*)d_ws;                     // ~252 MB used (ws ≈ 1.6 GB)
  unsigned short* Wb   = (unsigned short*)(ws);
  unsigned short* P0T  = (unsigned short*)(ws + (1L  << 20));  // [128][10048] bf16
  unsigned short* P1T  = (unsigned short*)(ws + (4L  << 20));  // [128][10048] bf16
  unsigned short* P2T  = (unsigned short*)(ws + (7L  << 20));  // [64][10048]  bf16
  float*          H0   = (float*)(ws + (9L  << 20));           // [10000][128] f32
  float*          H1   = (float*)(ws + (15L << 20));           // [10000][128] f32
  float*          Tb   = (float*)(ws + (21L << 20));           // [10000][64]  f32
  float*          part = (float*)(ws + (24L << 20));           // [4][10000][128] f32
  unsigned short* AdjB = (unsigned short*)(ws + (48L << 20));  // [10016][10048] bf16

  dim3 blk(256);
  const int TILES = 313;

  padzero<<<dim3(484), blk, 0, stream>>>(P0T, P1T, P2T, AdjB);
  wconv  <<<dim3(384), blk, 0, stream>>>(W0, W1, W2, Wp1, Wp2, Wb);

  // P0^T = (x @ W0^T + b0)^T   bf16 [128][LDP]
  gemm_k<128,1,false,false,true ,false,true ><<<dim3(TILES), blk, 0, stream>>>(
      x, 512, Wb, 512, b0, P0T, LDP, 10000, 512, nullptr, 0);
  // part[s] = Adj[:,ks] @ P0[ks,:]  (f32 A, split-K=4, mirrors Adj->bf16)
  gemm_k<128,4,false,true ,false,false,false><<<dim3(TILES,4), blk, 0, stream>>>(
      Adj, 10000, P0T, LDP, nullptr, part, 128, 10000, 10000, AdjB, LDP);
  // H0 = relu(sum part)
  reduce4<true ><<<dim3(1250), blk, 0, stream>>>(part, H0, 320000, 320000);
  // P1^T = (H0 @ W1^T + b1)^T
  gemm_k<128,1,false,false,true ,false,true ><<<dim3(TILES), blk, 0, stream>>>(
      H0, 128, Wb + 65536, 128, b1, P1T, LDP, 10000, 128, nullptr, 0);
  // part[s] = AdjB @ P1  (bf16 A via global_load_lds, split-K=4)
  gemm_k<128,4,true ,false,false,false,false><<<dim3(TILES,4), blk, 0, stream>>>(
      AdjB, LDP, P1T, LDP, nullptr, part, 128, 10000, 10000, nullptr, 0);
  // H1 = relu(sum part)
  reduce4<true ><<<dim3(1250), blk, 0, stream>>>(part, H1, 320000, 320000);
  // P2^T = (H1 @ W2^T + b2)^T   bf16 [64][LDP]
  gemm_k<64 ,1,false,false,true ,false,true ><<<dim3(TILES), blk, 0, stream>>>(
      H1, 128, Wb + 81920, 128, b2, P2T, LDP, 10000, 128, nullptr, 0);
  // part[s] = AdjB @ P2  (split-K=4)
  gemm_k<64 ,4,true ,false,false,false,false><<<dim3(TILES,4), blk, 0, stream>>>(
      AdjB, LDP, P2T, LDP, nullptr, part, 64, 10000, 10000, nullptr, 0);
  // emb = sum part  -> d_out second half
  reduce4<false><<<dim3(625), blk, 0, stream>>>(part, emb_out, 160000, 160000);
  // T = relu(emb @ Wp1^T + bp1)
  gemm_k<64 ,1,false,false,true ,true ,false><<<dim3(TILES), blk, 0, stream>>>(
      emb_out, 64, Wb + 90112, 64, bp1, Tb, 64, 10000, 64, nullptr, 0);
  // z = T @ Wp2^T + bp2  -> d_out first half
  gemm_k<64 ,1,false,false,true ,false,false><<<dim3(TILES), blk, 0, stream>>>(
      Tb, 64, Wb + 94208, 64, bp2, z_out, 64, 10000, 64, nullptr, 0);
}